// Round 1
// baseline (196.784 us; speedup 1.0000x reference)
//
#include <hip/hip_runtime.h>

// Ragged (values, offsets) -> dense [num_rows, 32] fp32.
// Output-centric: out[row][col] = col < len(row) ? values[offsets[row]+col] : 0
// One thread per output float4 (8 threads per row, DIM=32).
//
// v2 changes vs 193.5us baseline:
//  - Block = 32 rows. The 33 row offsets for the block are staged in LDS by
//    one coalesced load (33 threads) instead of every thread issuing two
//    scalar offset loads (16 redundant loads/row). Cuts one dependent
//    global-load round from every thread's critical path.
//  - Nontemporal load/store hints on values/out: 194 MB of single-use
//    streaming traffic, keep it from churning L2.
//
// Traffic floor: 134 MB write + 69 MB values read + 4 MB offsets read
// ~= 207 MB @ ~6.6 TB/s ~= 31 us for the kernel dispatch itself.

#define DIM 32
#define ROWS_PER_BLOCK 32
#define BLOCK 256          // ROWS_PER_BLOCK * (DIM/4)

typedef float f4 __attribute__((ext_vector_type(4)));

__global__ __launch_bounds__(BLOCK) void ragged_to_dense_kernel(
    const float* __restrict__ values,
    const int*   __restrict__ offsets,
    float*       __restrict__ out,
    int num_rows,
    int total_values)
{
    __shared__ int s_off[ROWS_PER_BLOCK + 1];

    const int tid  = threadIdx.x;
    const int row0 = blockIdx.x * ROWS_PER_BLOCK;

    // Stage the 33 offsets this block needs (offsets[row0 .. row0+32]).
    // offsets[num_rows] doesn't exist -> clamp to total_values.
    if (tid <= ROWS_PER_BLOCK) {
        const int idx = row0 + tid;
        s_off[tid] = (idx < num_rows) ? offsets[idx] : total_values;
    }
    __syncthreads();   // no thread returns before this point

    const int r_local = tid >> 3;           // 8 quad-threads per row
    const int row     = row0 + r_local;
    const int c0      = (tid & 7) << 2;     // first col of this quad

    const int start = s_off[r_local];
    const int len   = s_off[r_local + 1] - start;

    f4 v = (f4)0.0f;
    const float* src = values + start + c0;
    if (c0 + 4 <= len) {
        // Quad fully in range: one 16B vector load (4B-aligned is fine on gfx950).
        v = __builtin_nontemporal_load(reinterpret_cast<const f4*>(src));
    } else if (c0 < len) {
        // Partial tail quad (at most one per row): predicated scalar loads.
        v.x = __builtin_nontemporal_load(src);
        if (c0 + 1 < len) v.y = __builtin_nontemporal_load(src + 1);
        if (c0 + 2 < len) v.z = __builtin_nontemporal_load(src + 2);
        // c0+3 < len impossible here (would be the full-quad path)
    }
    // else: quad entirely past the row end -> zeros.

    if (row < num_rows) {
        // Same fully-coalesced mapping as v1: quad index g = blockIdx.x*256 + tid.
        __builtin_nontemporal_store(
            v, reinterpret_cast<f4*>(out) + (size_t)blockIdx.x * BLOCK + tid);
    }
}

extern "C" void kernel_launch(void* const* d_in, const int* in_sizes, int n_in,
                              void* d_out, int out_size, void* d_ws, size_t ws_size,
                              hipStream_t stream) {
    const float* values  = (const float*)d_in[0];
    const int*   offsets = (const int*)d_in[1];
    // d_in[2] is `dimension` (scalar 32) — DIM hard-coded.
    float* out = (float*)d_out;

    int total_values = in_sizes[0];     // 17,301,504
    int num_rows     = in_sizes[1];     // 1,048,576

    int grid = (num_rows + ROWS_PER_BLOCK - 1) / ROWS_PER_BLOCK;
    ragged_to_dense_kernel<<<grid, BLOCK, 0, stream>>>(
        values, offsets, out, num_rows, total_values);
}